// Round 8
// baseline (401.007 us; speedup 1.0000x reference)
//
#include <hip/hip_runtime.h>
#include <hip/hip_fp16.h>
#include <math.h>
#include <stdint.h>

#define NNODES 50000
#define NEDGES 800000
#define DIM 256
#define HEADS 4
#define DH 64
#define NEG_SLOPE 0.2f

#define CSR_NPB 1024
#define CSR_NB ((NNODES + CSR_NPB - 1) / CSR_NPB)  // 49

typedef _Float16 half8 __attribute__((ext_vector_type(8)));
typedef float floatx4 __attribute__((ext_vector_type(4)));

static __device__ __forceinline__ float h2f(unsigned short h) {
  __half x = *(const __half*)&h;
  return __half2float(x);
}
static __device__ __forceinline__ unsigned short f2h(float f) {
  __half x = __float2half(f);
  return *(const unsigned short*)&x;
}

// ---- W transpose + fp16 convert (both weights in one launch) ----------------
__global__ __launch_bounds__(256) void wt_k(const float* __restrict__ W1,
                                            const float* __restrict__ W2,
                                            _Float16* __restrict__ WT1,
                                            _Float16* __restrict__ WT2) {
  int b = blockIdx.x;
  const float* W = (b < 256) ? W1 : W2;
  _Float16* WT = (b < 256) ? WT1 : WT2;
  int n = b & 255;
  int k = threadIdx.x;
  WT[n * 256 + k] = (_Float16)W[k * 256 + n];
}

// ------- GEMM + fused el/er: C[M,256](fp16) = A[M,256] @ W ; el/er[M,4] ------
// NO-LDS / NO-BARRIER version. MFMA f32_16x16x32_f16, operands swapped:
// MFMA-A = W^T (m=out-feat), MFMA-B = activations (n=node).
// Per-lane fragment reads are 16-B contiguous global loads:
//   B(act) frag i: A[row0+i*16+m16][k0+q*8 .. +7]  (16 rows x 64-B lines,
//     fully consumed across q; A read exactly once per block, L1-shared by waves)
//   A(wt) frag i: WT[w*64+i*16+m16][k0+q*8 .. +7]  (128 KB WT is L1/L2-hot,
//     identical across all blocks)
// K-loop fully unrolled -> compiler hoists loads across MFMAs (no barriers to
// drain). C/D: n=lane&15, m=q*4+reg.
template <typename AT>
__global__ __launch_bounds__(256) void gemm_k(const AT* __restrict__ A,
                                              const _Float16* __restrict__ BT,
                                              const float* __restrict__ alw,
                                              const float* __restrict__ arw,
                                              unsigned short* __restrict__ Cb,
                                              float* __restrict__ el,
                                              float* __restrict__ er, int M) {
  int t = threadIdx.x;
  int lane = t & 63, w = t >> 6;
  int m16 = lane & 15, q = lane >> 4;
  int row0 = blockIdx.x * 64;
  floatx4 acc[4][4];
#pragma unroll
  for (int i = 0; i < 4; ++i)
#pragma unroll
    for (int j = 0; j < 4; ++j) acc[i][j] = (floatx4){0.f, 0.f, 0.f, 0.f};

  // al/ar fragments: alv[ni][r] corresponds to feat w*64+ni*16+q*4+r
  float4 alv[4], arv[4];
#pragma unroll
  for (int ni = 0; ni < 4; ++ni) {
    alv[ni] = *(const float4*)&alw[w * 64 + ni * 16 + q * 4];
    arv[ni] = *(const float4*)&arw[w * 64 + ni * 16 + q * 4];
  }

  // per-frag base pointers (row clamped for OOB-safe loads; stores guarded)
  const AT* ab[4];
  const _Float16* bb[4];
#pragma unroll
  for (int i = 0; i < 4; ++i) {
    int ar = row0 + i * 16 + m16;
    if (ar > M - 1) ar = M - 1;
    ab[i] = &A[(size_t)ar * DIM + q * 8];
    bb[i] = &BT[(size_t)(w * 64 + i * 16 + m16) * DIM + q * 8];
  }

#pragma unroll
  for (int k0 = 0; k0 < DIM; k0 += 32) {
    half8 wf[4], af[4];
#pragma unroll
    for (int i = 0; i < 4; ++i) wf[i] = *(const half8*)(bb[i] + k0);
#pragma unroll
    for (int i = 0; i < 4; ++i) {
      if constexpr (sizeof(AT) == 4) {
        float4 x0 = *(const float4*)(ab[i] + k0);
        float4 x1 = *(const float4*)(ab[i] + k0 + 4);
        half8 hv;
        hv[0] = (_Float16)x0.x; hv[1] = (_Float16)x0.y;
        hv[2] = (_Float16)x0.z; hv[3] = (_Float16)x0.w;
        hv[4] = (_Float16)x1.x; hv[5] = (_Float16)x1.y;
        hv[6] = (_Float16)x1.z; hv[7] = (_Float16)x1.w;
        af[i] = hv;
      } else {
        af[i] = *(const half8*)(ab[i] + k0);
      }
    }
#pragma unroll
    for (int mi = 0; mi < 4; ++mi)
#pragma unroll
      for (int ni = 0; ni < 4; ++ni)
        acc[mi][ni] = __builtin_amdgcn_mfma_f32_16x16x32_f16(
            wf[ni], af[mi], acc[mi][ni], 0, 0, 0);
  }

#pragma unroll
  for (int mi = 0; mi < 4; ++mi) {
    int node = row0 + mi * 16 + m16;
    // el/er: dot over feats (regs+q), reduce across q groups
    float pl = 0.f, pr = 0.f;
#pragma unroll
    for (int ni = 0; ni < 4; ++ni) {
      pl += acc[mi][ni][0] * alv[ni].x + acc[mi][ni][1] * alv[ni].y +
            acc[mi][ni][2] * alv[ni].z + acc[mi][ni][3] * alv[ni].w;
      pr += acc[mi][ni][0] * arv[ni].x + acc[mi][ni][1] * arv[ni].y +
            acc[mi][ni][2] * arv[ni].z + acc[mi][ni][3] * arv[ni].w;
    }
    pl += __shfl_xor(pl, 16, 64); pl += __shfl_xor(pl, 32, 64);
    pr += __shfl_xor(pr, 16, 64); pr += __shfl_xor(pr, 32, 64);
    if (q == 0 && node < M) {
      el[node * HEADS + w] = pl;
      er[node * HEADS + w] = pr;
    }
    if (node < M) {
#pragma unroll
      for (int ni = 0; ni < 4; ++ni) {
        ushort4 o;
        o.x = f2h(acc[mi][ni][0]); o.y = f2h(acc[mi][ni][1]);
        o.z = f2h(acc[mi][ni][2]); o.w = f2h(acc[mi][ni][3]);
        *(ushort4*)&Cb[(size_t)node * DIM + w * 64 + ni * 16 + q * 4] = o;
      }
    }
  }
}

// ---------------- CSR build ----------------
__global__ __launch_bounds__(256) void deg_k(const int* __restrict__ dst,
                                             int* __restrict__ deg) {
  int e4 = (blockIdx.x * 256 + threadIdx.x) * 4;
  if (e4 < NEDGES) {
    int4 d = *(const int4*)&dst[e4];
    atomicAdd(&deg[d.x], 1);
    atomicAdd(&deg[d.y], 1);
    atomicAdd(&deg[d.z], 1);
    atomicAdd(&deg[d.w], 1);
  }
}

__global__ __launch_bounds__(256) void csr_part_k(const int* __restrict__ deg,
                                                  int* __restrict__ bsum) {
  __shared__ int ws[4];
  int t = threadIdx.x, lane = t & 63, w = t >> 6;
  int idx = blockIdx.x * CSR_NPB + t * 4;
  int s = 0;
  if (idx < NNODES) {
    int4 v = *(const int4*)&deg[idx];
    s = v.x + v.y + v.z + v.w;
  }
#pragma unroll
  for (int off = 1; off < 64; off <<= 1) s += __shfl_xor(s, off, 64);
  if (lane == 0) ws[w] = s;
  __syncthreads();
  if (t == 0) bsum[blockIdx.x] = ws[0] + ws[1] + ws[2] + ws[3];
}

// 1 block, 64 threads: scan block sums; also write row_ptr[N].
__global__ __launch_bounds__(64) void csr_mid_k(const int* __restrict__ bsum,
                                                int* __restrict__ bbase,
                                                int* __restrict__ row_ptr) {
  int t = threadIdx.x;
  int v = (t < CSR_NB) ? bsum[t] : 0;
  int incl = v;
#pragma unroll
  for (int off = 1; off < 64; off <<= 1) {
    int u = __shfl_up(incl, off, 64);
    if (t >= off) incl += u;
  }
  if (t < CSR_NB) bbase[t] = incl - v;
  if (t == 0) row_ptr[NNODES] = NEDGES;
}

__global__ __launch_bounds__(256) void csr_emit_k(const int* __restrict__ deg,
                                                  const int* __restrict__ bbase,
                                                  int* __restrict__ row_ptr,
                                                  int* __restrict__ cursor) {
  __shared__ int ws[4];
  int t = threadIdx.x, lane = t & 63, w = t >> 6;
  int idx = blockIdx.x * CSR_NPB + t * 4;
  int4 v = make_int4(0, 0, 0, 0);
  if (idx < NNODES) v = *(const int4*)&deg[idx];
  int s0 = v.x, s1 = s0 + v.y, s2 = s1 + v.z, s3 = s2 + v.w;
  int incl = s3;
#pragma unroll
  for (int off = 1; off < 64; off <<= 1) {
    int u = __shfl_up(incl, off, 64);
    if (lane >= off) incl += u;
  }
  if (lane == 63) ws[w] = incl;
  __syncthreads();
  int wbase = 0;
#pragma unroll
  for (int i = 0; i < 4; ++i)
    if (i < w) wbase += ws[i];
  int base = bbase[blockIdx.x] + wbase + incl - s3;
  if (idx < NNODES) {
    int4 rp = make_int4(base, base + s0, base + s1, base + s2);
    *(int4*)&row_ptr[idx] = rp;
    *(int4*)&cursor[idx] = rp;
  }
}

// scatter: srcoff[pos] = byte offset of the source node's fp16 feat row.
__global__ __launch_bounds__(256) void scatter_k(const int* __restrict__ src,
                                                 const int* __restrict__ dst,
                                                 int* __restrict__ cursor,
                                                 int* __restrict__ srcoff) {
  int e4 = (blockIdx.x * 256 + threadIdx.x) * 4;
  if (e4 < NEDGES) {
    int4 s = *(const int4*)&src[e4];
    int4 d = *(const int4*)&dst[e4];
    int p;
    p = atomicAdd(&cursor[d.x], 1); srcoff[p] = s.x << 9;
    p = atomicAdd(&cursor[d.y], 1); srcoff[p] = s.y << 9;
    p = atomicAdd(&cursor[d.z], 1); srcoff[p] = s.z << 9;
    p = atomicAdd(&cursor[d.w], 1); srcoff[p] = s.w << 9;
  }
}

// ---------- fused score + softmax + aggregation (gather over CSR) ------------
// One wave per node (block = 4 waves = 4 nodes). lane*4 = global feature idx,
// head h = lane>>4. Per 16-edge chunk: lanes 0-15 preload srcoff; lane L
// computes alpha of edge L>>2, head L&3 inline from el-gather (800 KB
// L2-resident) + er[n] — ONE el load + ONE exp per lane per chunk; per edge
// one ushort4 load/lane covers the full 512 B feat row; alpha broadcast via
// bpermute (idle DS pipe). Tail edges: alpha=0 guards; their soff=0 -> feat
// row 0 (L1-hot, contributes 0). FULL 16-edge unroll, no early break ->
// 16 independent feat loads in flight per chunk (4x the MLP of the r4 body).
// segment_max dropped: scores O(1), fp32 exp safe, alpha identical.
template <int MODE>  // 1 = ELU -> fp16 hidden; 2 = mean over heads -> fp32 out
__global__ __launch_bounds__(256) void agg_k(const unsigned short* __restrict__ feat,
                                             const float* __restrict__ el,
                                             const float* __restrict__ er,
                                             const int* __restrict__ row_ptr,
                                             const int* __restrict__ srcoff,
                                             void* __restrict__ outp) {
  int lane = threadIdx.x & 63;
  int w = threadIdx.x >> 6;
  int n = blockIdx.x * 4 + w;
  if (n >= NNODES) return;
  int h = lane >> 4;
  int hsel = lane & 3;
  int esel = lane >> 2;
  int beg = row_ptr[n], end = row_ptr[n + 1];
  float erv = er[n * HEADS + hsel];
  int laneByte = lane * 8;
  const char* fb = (const char*)feat;
  const char* elb = (const char*)el;
  float a0 = 0.f, a1 = 0.f, a2 = 0.f, a3 = 0.f, sume = 0.f;
  for (int c0 = beg; c0 < end; c0 += 16) {
    int soff = 0;
    if (lane < 16 && c0 + lane < end) soff = srcoff[c0 + lane];
    float av = 0.f;
    if (c0 + esel < end) {
      int sE = __shfl(soff, esel, 64);
      float elv = *(const float*)(elb + (sE >> 5) + hsel * 4);  // el[s][hsel]
      float v = elv + erv;
      v = v > 0.f ? v : NEG_SLOPE * v;
      av = __expf(v);
    }
#pragma unroll
    for (int j = 0; j < 16; ++j) {
      int sB = __shfl(soff, j, 64);
      float a = __shfl(av, 4 * j + h, 64);
      ushort4 u = *(const ushort4*)(fb + (sB + laneByte));
      a0 += h2f(u.x) * a;
      a1 += h2f(u.y) * a;
      a2 += h2f(u.z) * a;
      a3 += h2f(u.w) * a;
      sume += a;
    }
  }
  float inv = 1.f / fmaxf(sume, 1e-9f);
  a0 *= inv; a1 *= inv; a2 *= inv; a3 *= inv;
  if (MODE == 1) {
    a0 = a0 > 0.f ? a0 : (__expf(a0) - 1.f);
    a1 = a1 > 0.f ? a1 : (__expf(a1) - 1.f);
    a2 = a2 > 0.f ? a2 : (__expf(a2) - 1.f);
    a3 = a3 > 0.f ? a3 : (__expf(a3) - 1.f);
    ushort4 o;
    o.x = f2h(a0); o.y = f2h(a1); o.z = f2h(a2); o.w = f2h(a3);
    *(ushort4*)((char*)outp + (size_t)n * 512 + laneByte) = o;
  } else {
    a0 += __shfl_xor(a0, 16, 64); a0 += __shfl_xor(a0, 32, 64);
    a1 += __shfl_xor(a1, 16, 64); a1 += __shfl_xor(a1, 32, 64);
    a2 += __shfl_xor(a2, 16, 64); a2 += __shfl_xor(a2, 32, 64);
    a3 += __shfl_xor(a3, 16, 64); a3 += __shfl_xor(a3, 32, 64);
    if (lane < 16) {
      float4 o = make_float4(a0 * 0.25f, a1 * 0.25f, a2 * 0.25f, a3 * 0.25f);
      *(float4*)((float*)outp + (size_t)n * 64 + lane * 4) = o;
    }
  }
}

extern "C" void kernel_launch(void* const* d_in, const int* in_sizes, int n_in,
                              void* d_out, int out_size, void* d_ws, size_t ws_size,
                              hipStream_t stream) {
  const float* feature = (const float*)d_in[0];
  const float* W1 = (const float*)d_in[1];
  const float* al1 = (const float*)d_in[2];
  const float* ar1 = (const float*)d_in[3];
  const float* W2 = (const float*)d_in[4];
  const float* al2 = (const float*)d_in[5];
  const float* ar2 = (const float*)d_in[6];
  const int* src = (const int*)d_in[7];
  const int* dst = (const int*)d_in[8];
  float* out = (float*)d_out;

  uintptr_t p = (uintptr_t)d_ws;
  auto alloc = [&](size_t bytes) -> void* {
    uintptr_t cur = (p + 255) & ~(uintptr_t)255;
    p = cur + bytes;
    return (void*)cur;
  };
  unsigned short* featH = (unsigned short*)alloc((size_t)NNODES * DIM * 2);  // 25.6 MB
  unsigned short* hidH  = (unsigned short*)alloc((size_t)NNODES * DIM * 2);  // 25.6 MB
  _Float16* WT1 = (_Float16*)alloc((size_t)256 * 256 * 2);
  _Float16* WT2 = (_Float16*)alloc((size_t)256 * 256 * 2);
  float* el    = (float*)alloc((size_t)NNODES * HEADS * 4);
  float* er    = (float*)alloc((size_t)NNODES * HEADS * 4);
  int* deg     = (int*)alloc((size_t)NNODES * 4);
  int* row_ptr = (int*)alloc((size_t)(NNODES + 1) * 4);
  int* cursor  = (int*)alloc((size_t)NNODES * 4);
  int* srcoff  = (int*)alloc((size_t)NEDGES * 4);
  int* bsum    = (int*)alloc((size_t)CSR_NB * 4);
  int* bbase   = (int*)alloc((size_t)CSR_NB * 4);

  const int E4B = (NEDGES / 4 + 255) / 256;
  const int MB = (NNODES + 63) / 64;
  const int AB = (NNODES + 3) / 4;

  // ---- weights + CSR build (CSR shared by both layers) ----
  wt_k<<<512, 256, 0, stream>>>(W1, W2, WT1, WT2);
  hipMemsetAsync(deg, 0, (size_t)NNODES * 4, stream);
  deg_k<<<E4B, 256, 0, stream>>>(dst, deg);
  csr_part_k<<<CSR_NB, 256, 0, stream>>>(deg, bsum);
  csr_mid_k<<<1, 64, 0, stream>>>(bsum, bbase, row_ptr);
  csr_emit_k<<<CSR_NB, 256, 0, stream>>>(deg, bbase, row_ptr, cursor);
  scatter_k<<<E4B, 256, 0, stream>>>(src, dst, cursor, srcoff);

  // ---- layer 1: GEMM(+el/er) -> fused score/softmax/agg (+ELU, fp16) ----
  gemm_k<float><<<MB, 256, 0, stream>>>(feature, WT1, al1, ar1, featH, el, er, NNODES);
  agg_k<1><<<AB, 256, 0, stream>>>(featH, el, er, row_ptr, srcoff, hidH);

  // ---- layer 2: GEMM(+el/er) -> fused agg + head-mean -> d_out ----
  gemm_k<_Float16><<<MB, 256, 0, stream>>>((const _Float16*)hidH, WT2, al2, ar2,
                                           featH, el, er, NNODES);
  agg_k<2><<<AB, 256, 0, stream>>>(featH, el, er, row_ptr, srcoff, out);
}

// Round 9
// 356.518 us; speedup vs baseline: 1.1248x; 1.1248x over previous
//
#include <hip/hip_runtime.h>
#include <hip/hip_fp16.h>
#include <math.h>
#include <stdint.h>

#define NNODES 50000
#define NEDGES 800000
#define DIM 256
#define HEADS 4
#define DH 64
#define NEG_SLOPE 0.2f

#define CSR_NPB 1024
#define CSR_NB ((NNODES + CSR_NPB - 1) / CSR_NPB)  // 49

typedef _Float16 half8 __attribute__((ext_vector_type(8)));
typedef float floatx4 __attribute__((ext_vector_type(4)));

static __device__ __forceinline__ float h2f(unsigned short h) {
  __half x = *(const __half*)&h;
  return __half2float(x);
}
static __device__ __forceinline__ unsigned short f2h(float f) {
  __half x = __float2half(f);
  return *(const unsigned short*)&x;
}

// ---- W transpose + fp16 convert (both weights in one launch) ----------------
__global__ __launch_bounds__(256) void wt_k(const float* __restrict__ W1,
                                            const float* __restrict__ W2,
                                            _Float16* __restrict__ WT1,
                                            _Float16* __restrict__ WT2) {
  int b = blockIdx.x;
  const float* W = (b < 256) ? W1 : W2;
  _Float16* WT = (b < 256) ? WT1 : WT2;
  int n = b & 255;
  int k = threadIdx.x;
  WT[n * 256 + k] = (_Float16)W[k * 256 + n];
}

// ------- GEMM + fused el/er: C[M,256](fp16) = A[M,256] @ W ; el/er[M,4] ------
// LDS-staged, BK=64 (4 K-steps, half the barrier drains of the r7 BK=32
// version; 32 MFMAs per barrier pair). MFMA f32_16x16x32_f16, operands
// swapped: MFMA-A = W^T (m=out-feat), MFMA-B = activations (n=node).
// Layouts (HW-verified m89/m91/m120):
//   A-op: lane holds A[m=lane&15][k=q*8+j]; B-op: lane holds B[k=q*8+j][n=lane&15]
//   C/D: n=lane&15, m=q*4+reg
// LDS 45 KB -> 3 blocks/CU (matches grid 3.05 blocks/CU). Row stride 72
// halves (144 B): b128 frag reads are 2-way bank aliased = free (m136).
template <typename AT>
__global__ __launch_bounds__(256) void gemm_k(const AT* __restrict__ A,
                                              const _Float16* __restrict__ BT,
                                              const float* __restrict__ alw,
                                              const float* __restrict__ arw,
                                              unsigned short* __restrict__ Cb,
                                              float* __restrict__ el,
                                              float* __restrict__ er, int M) {
  __shared__ __attribute__((aligned(16))) _Float16 Asl[64][72];
  __shared__ __attribute__((aligned(16))) _Float16 Bsl[256][72];
  int t = threadIdx.x;
  int lane = t & 63, w = t >> 6;
  int m16 = lane & 15, q = lane >> 4;
  int row0 = blockIdx.x * 64;
  floatx4 acc[4][4];
#pragma unroll
  for (int i = 0; i < 4; ++i)
#pragma unroll
    for (int j = 0; j < 4; ++j) acc[i][j] = (floatx4){0.f, 0.f, 0.f, 0.f};

  // al/ar fragments: alv[ni][r] corresponds to feat w*64+ni*16+q*4+r
  float4 alv[4], arv[4];
#pragma unroll
  for (int ni = 0; ni < 4; ++ni) {
    alv[ni] = *(const float4*)&alw[w * 64 + ni * 16 + q * 4];
    arv[ni] = *(const float4*)&arw[w * 64 + ni * 16 + q * 4];
  }

  int arow = t >> 2, akoff = (t & 3) * 16;  // A staging: row, 16-elem k-chunk

  for (int k0 = 0; k0 < DIM; k0 += 64) {
    // ---- stage A tile (64 rows x 64 k) ----
    if constexpr (sizeof(AT) == 4) {
      float4 x0 = make_float4(0.f, 0.f, 0.f, 0.f), x1 = x0, x2 = x0, x3 = x0;
      if (row0 + arow < M) {
        const float* ap = (const float*)&A[(size_t)(row0 + arow) * DIM + k0 + akoff];
        x0 = *(const float4*)ap;
        x1 = *(const float4*)(ap + 4);
        x2 = *(const float4*)(ap + 8);
        x3 = *(const float4*)(ap + 12);
      }
      half8 h0, h1;
      h0[0] = (_Float16)x0.x; h0[1] = (_Float16)x0.y;
      h0[2] = (_Float16)x0.z; h0[3] = (_Float16)x0.w;
      h0[4] = (_Float16)x1.x; h0[5] = (_Float16)x1.y;
      h0[6] = (_Float16)x1.z; h0[7] = (_Float16)x1.w;
      h1[0] = (_Float16)x2.x; h1[1] = (_Float16)x2.y;
      h1[2] = (_Float16)x2.z; h1[3] = (_Float16)x2.w;
      h1[4] = (_Float16)x3.x; h1[5] = (_Float16)x3.y;
      h1[6] = (_Float16)x3.z; h1[7] = (_Float16)x3.w;
      *(half8*)&Asl[arow][akoff] = h0;
      *(half8*)&Asl[arow][akoff + 8] = h1;
    } else {
      int4 x0 = make_int4(0, 0, 0, 0), x1 = x0;
      if (row0 + arow < M) {
        const AT* ap = &A[(size_t)(row0 + arow) * DIM + k0 + akoff];
        x0 = *(const int4*)ap;
        x1 = *(const int4*)(ap + 8);
      }
      *(int4*)&Asl[arow][akoff] = x0;
      *(int4*)&Asl[arow][akoff + 8] = x1;
    }
    // ---- stage B tile (256 cols x 64 k): thread t = col ----
    {
      const _Float16* bp = &BT[(size_t)t * 256 + k0];
#pragma unroll
      for (int c = 0; c < 8; ++c)
        *(int4*)&Bsl[t][c * 8] = *(const int4*)(bp + c * 8);
    }
    __syncthreads();
    half8 wf[2][4], af[2][4];
#pragma unroll
    for (int s = 0; s < 2; ++s)
#pragma unroll
      for (int i = 0; i < 4; ++i) {
        wf[s][i] = *(const half8*)&Bsl[w * 64 + i * 16 + m16][s * 32 + q * 8];
        af[s][i] = *(const half8*)&Asl[i * 16 + m16][s * 32 + q * 8];
      }
#pragma unroll
    for (int s = 0; s < 2; ++s)
#pragma unroll
      for (int mi = 0; mi < 4; ++mi)
#pragma unroll
        for (int ni = 0; ni < 4; ++ni)
          acc[mi][ni] = __builtin_amdgcn_mfma_f32_16x16x32_f16(
              wf[s][ni], af[s][mi], acc[mi][ni], 0, 0, 0);
    __syncthreads();
  }

#pragma unroll
  for (int mi = 0; mi < 4; ++mi) {
    int node = row0 + mi * 16 + m16;
    // el/er: dot over feats (regs+q), reduce across q groups
    float pl = 0.f, pr = 0.f;
#pragma unroll
    for (int ni = 0; ni < 4; ++ni) {
      pl += acc[mi][ni][0] * alv[ni].x + acc[mi][ni][1] * alv[ni].y +
            acc[mi][ni][2] * alv[ni].z + acc[mi][ni][3] * alv[ni].w;
      pr += acc[mi][ni][0] * arv[ni].x + acc[mi][ni][1] * arv[ni].y +
            acc[mi][ni][2] * arv[ni].z + acc[mi][ni][3] * arv[ni].w;
    }
    pl += __shfl_xor(pl, 16, 64); pl += __shfl_xor(pl, 32, 64);
    pr += __shfl_xor(pr, 16, 64); pr += __shfl_xor(pr, 32, 64);
    if (q == 0 && node < M) {
      el[node * HEADS + w] = pl;
      er[node * HEADS + w] = pr;
    }
    if (node < M) {
#pragma unroll
      for (int ni = 0; ni < 4; ++ni) {
        ushort4 o;
        o.x = f2h(acc[mi][ni][0]); o.y = f2h(acc[mi][ni][1]);
        o.z = f2h(acc[mi][ni][2]); o.w = f2h(acc[mi][ni][3]);
        *(ushort4*)&Cb[(size_t)node * DIM + w * 64 + ni * 16 + q * 4] = o;
      }
    }
  }
}

// ---------------- CSR build ----------------
// 8 edges/thread, grouped fire-and-forget atomics.
__global__ __launch_bounds__(256) void deg_k(const int* __restrict__ dst,
                                             int* __restrict__ deg) {
  int e8 = (blockIdx.x * 256 + threadIdx.x) * 8;
  if (e8 < NEDGES) {
    int4 d0 = *(const int4*)&dst[e8];
    int4 d1 = *(const int4*)&dst[e8 + 4];
    atomicAdd(&deg[d0.x], 1);
    atomicAdd(&deg[d0.y], 1);
    atomicAdd(&deg[d0.z], 1);
    atomicAdd(&deg[d0.w], 1);
    atomicAdd(&deg[d1.x], 1);
    atomicAdd(&deg[d1.y], 1);
    atomicAdd(&deg[d1.z], 1);
    atomicAdd(&deg[d1.w], 1);
  }
}

__global__ __launch_bounds__(256) void csr_part_k(const int* __restrict__ deg,
                                                  int* __restrict__ bsum) {
  __shared__ int ws[4];
  int t = threadIdx.x, lane = t & 63, w = t >> 6;
  int idx = blockIdx.x * CSR_NPB + t * 4;
  int s = 0;
  if (idx < NNODES) {
    int4 v = *(const int4*)&deg[idx];
    s = v.x + v.y + v.z + v.w;
  }
#pragma unroll
  for (int off = 1; off < 64; off <<= 1) s += __shfl_xor(s, off, 64);
  if (lane == 0) ws[w] = s;
  __syncthreads();
  if (t == 0) bsum[blockIdx.x] = ws[0] + ws[1] + ws[2] + ws[3];
}

// 1 block, 64 threads: scan block sums; also write row_ptr[N].
__global__ __launch_bounds__(64) void csr_mid_k(const int* __restrict__ bsum,
                                                int* __restrict__ bbase,
                                                int* __restrict__ row_ptr) {
  int t = threadIdx.x;
  int v = (t < CSR_NB) ? bsum[t] : 0;
  int incl = v;
#pragma unroll
  for (int off = 1; off < 64; off <<= 1) {
    int u = __shfl_up(incl, off, 64);
    if (t >= off) incl += u;
  }
  if (t < CSR_NB) bbase[t] = incl - v;
  if (t == 0) row_ptr[NNODES] = NEDGES;
}

__global__ __launch_bounds__(256) void csr_emit_k(const int* __restrict__ deg,
                                                  const int* __restrict__ bbase,
                                                  int* __restrict__ row_ptr,
                                                  int* __restrict__ cursor) {
  __shared__ int ws[4];
  int t = threadIdx.x, lane = t & 63, w = t >> 6;
  int idx = blockIdx.x * CSR_NPB + t * 4;
  int4 v = make_int4(0, 0, 0, 0);
  if (idx < NNODES) v = *(const int4*)&deg[idx];
  int s0 = v.x, s1 = s0 + v.y, s2 = s1 + v.z, s3 = s2 + v.w;
  int incl = s3;
#pragma unroll
  for (int off = 1; off < 64; off <<= 1) {
    int u = __shfl_up(incl, off, 64);
    if (lane >= off) incl += u;
  }
  if (lane == 63) ws[w] = incl;
  __syncthreads();
  int wbase = 0;
#pragma unroll
  for (int i = 0; i < 4; ++i)
    if (i < w) wbase += ws[i];
  int base = bbase[blockIdx.x] + wbase + incl - s3;
  if (idx < NNODES) {
    int4 rp = make_int4(base, base + s0, base + s1, base + s2);
    *(int4*)&row_ptr[idx] = rp;
    *(int4*)&cursor[idx] = rp;
  }
}

// scatter: srcoff[pos] = byte offset of source node's fp16 feat row.
// 8 edges/thread; all 8 atomics issued before the 8 dependent stores ->
// 8 independent latency chains per thread (2x the r8 MLP).
__global__ __launch_bounds__(256) void scatter_k(const int* __restrict__ src,
                                                 const int* __restrict__ dst,
                                                 int* __restrict__ cursor,
                                                 int* __restrict__ srcoff) {
  int e8 = (blockIdx.x * 256 + threadIdx.x) * 8;
  if (e8 < NEDGES) {
    int4 s0 = *(const int4*)&src[e8];
    int4 s1 = *(const int4*)&src[e8 + 4];
    int4 d0 = *(const int4*)&dst[e8];
    int4 d1 = *(const int4*)&dst[e8 + 4];
    int p0 = atomicAdd(&cursor[d0.x], 1);
    int p1 = atomicAdd(&cursor[d0.y], 1);
    int p2 = atomicAdd(&cursor[d0.z], 1);
    int p3 = atomicAdd(&cursor[d0.w], 1);
    int p4 = atomicAdd(&cursor[d1.x], 1);
    int p5 = atomicAdd(&cursor[d1.y], 1);
    int p6 = atomicAdd(&cursor[d1.z], 1);
    int p7 = atomicAdd(&cursor[d1.w], 1);
    srcoff[p0] = s0.x << 9;
    srcoff[p1] = s0.y << 9;
    srcoff[p2] = s0.z << 9;
    srcoff[p3] = s0.w << 9;
    srcoff[p4] = s1.x << 9;
    srcoff[p5] = s1.y << 9;
    srcoff[p6] = s1.z << 9;
    srcoff[p7] = s1.w << 9;
  }
}

// ---------- fused score + softmax + aggregation (gather over CSR) ------------
// One wave per node (block = 4 waves = 4 nodes). lane*4 = global feature idx,
// head h = lane>>4. Per 16-edge chunk: lanes 0-15 preload srcoff; lane L
// computes alpha of edge L>>2, head L&3 inline from el-gather (800 KB
// L2-resident) + er[n] — ONE el load + ONE exp per lane per chunk; per edge
// one ushort4 load/lane covers the full 512 B feat row; alpha broadcast via
// bpermute (idle DS pipe). Tail edges: alpha=0 guards; their soff=0 -> feat
// row 0 (L1-hot, contributes 0). Full 16-edge unroll -> 16 independent feat
// loads in flight per chunk.
// segment_max dropped: scores O(1), fp32 exp safe, alpha identical.
template <int MODE>  // 1 = ELU -> fp16 hidden; 2 = mean over heads -> fp32 out
__global__ __launch_bounds__(256) void agg_k(const unsigned short* __restrict__ feat,
                                             const float* __restrict__ el,
                                             const float* __restrict__ er,
                                             const int* __restrict__ row_ptr,
                                             const int* __restrict__ srcoff,
                                             void* __restrict__ outp) {
  int lane = threadIdx.x & 63;
  int w = threadIdx.x >> 6;
  int n = blockIdx.x * 4 + w;
  if (n >= NNODES) return;
  int h = lane >> 4;
  int hsel = lane & 3;
  int esel = lane >> 2;
  int beg = row_ptr[n], end = row_ptr[n + 1];
  float erv = er[n * HEADS + hsel];
  int laneByte = lane * 8;
  const char* fb = (const char*)feat;
  const char* elb = (const char*)el;
  float a0 = 0.f, a1 = 0.f, a2 = 0.f, a3 = 0.f, sume = 0.f;
  for (int c0 = beg; c0 < end; c0 += 16) {
    int soff = 0;
    if (lane < 16 && c0 + lane < end) soff = srcoff[c0 + lane];
    float av = 0.f;
    if (c0 + esel < end) {
      int sE = __shfl(soff, esel, 64);
      float elv = *(const float*)(elb + (sE >> 5) + hsel * 4);  // el[s][hsel]
      float v = elv + erv;
      v = v > 0.f ? v : NEG_SLOPE * v;
      av = __expf(v);
    }
#pragma unroll
    for (int j = 0; j < 16; ++j) {
      int sB = __shfl(soff, j, 64);
      float a = __shfl(av, 4 * j + h, 64);
      ushort4 u = *(const ushort4*)(fb + (sB + laneByte));
      a0 += h2f(u.x) * a;
      a1 += h2f(u.y) * a;
      a2 += h2f(u.z) * a;
      a3 += h2f(u.w) * a;
      sume += a;
    }
  }
  float inv = 1.f / fmaxf(sume, 1e-9f);
  a0 *= inv; a1 *= inv; a2 *= inv; a3 *= inv;
  if (MODE == 1) {
    a0 = a0 > 0.f ? a0 : (__expf(a0) - 1.f);
    a1 = a1 > 0.f ? a1 : (__expf(a1) - 1.f);
    a2 = a2 > 0.f ? a2 : (__expf(a2) - 1.f);
    a3 = a3 > 0.f ? a3 : (__expf(a3) - 1.f);
    ushort4 o;
    o.x = f2h(a0); o.y = f2h(a1); o.z = f2h(a2); o.w = f2h(a3);
    *(ushort4*)((char*)outp + (size_t)n * 512 + laneByte) = o;
  } else {
    a0 += __shfl_xor(a0, 16, 64); a0 += __shfl_xor(a0, 32, 64);
    a1 += __shfl_xor(a1, 16, 64); a1 += __shfl_xor(a1, 32, 64);
    a2 += __shfl_xor(a2, 16, 64); a2 += __shfl_xor(a2, 32, 64);
    a3 += __shfl_xor(a3, 16, 64); a3 += __shfl_xor(a3, 32, 64);
    if (lane < 16) {
      float4 o = make_float4(a0 * 0.25f, a1 * 0.25f, a2 * 0.25f, a3 * 0.25f);
      *(float4*)((float*)outp + (size_t)n * 64 + lane * 4) = o;
    }
  }
}

extern "C" void kernel_launch(void* const* d_in, const int* in_sizes, int n_in,
                              void* d_out, int out_size, void* d_ws, size_t ws_size,
                              hipStream_t stream) {
  const float* feature = (const float*)d_in[0];
  const float* W1 = (const float*)d_in[1];
  const float* al1 = (const float*)d_in[2];
  const float* ar1 = (const float*)d_in[3];
  const float* W2 = (const float*)d_in[4];
  const float* al2 = (const float*)d_in[5];
  const float* ar2 = (const float*)d_in[6];
  const int* src = (const int*)d_in[7];
  const int* dst = (const int*)d_in[8];
  float* out = (float*)d_out;

  uintptr_t p = (uintptr_t)d_ws;
  auto alloc = [&](size_t bytes) -> void* {
    uintptr_t cur = (p + 255) & ~(uintptr_t)255;
    p = cur + bytes;
    return (void*)cur;
  };
  unsigned short* featH = (unsigned short*)alloc((size_t)NNODES * DIM * 2);  // 25.6 MB
  unsigned short* hidH  = (unsigned short*)alloc((size_t)NNODES * DIM * 2);  // 25.6 MB
  _Float16* WT1 = (_Float16*)alloc((size_t)256 * 256 * 2);
  _Float16* WT2 = (_Float16*)alloc((size_t)256 * 256 * 2);
  float* el    = (float*)alloc((size_t)NNODES * HEADS * 4);
  float* er    = (float*)alloc((size_t)NNODES * HEADS * 4);
  int* deg     = (int*)alloc((size_t)NNODES * 4);
  int* row_ptr = (int*)alloc((size_t)(NNODES + 1) * 4);
  int* cursor  = (int*)alloc((size_t)NNODES * 4);
  int* srcoff  = (int*)alloc((size_t)NEDGES * 4);
  int* bsum    = (int*)alloc((size_t)CSR_NB * 4);
  int* bbase   = (int*)alloc((size_t)CSR_NB * 4);

  const int E8B = (NEDGES / 8 + 255) / 256;  // 391
  const int MB = (NNODES + 63) / 64;
  const int AB = (NNODES + 3) / 4;

  // ---- weights + CSR build (CSR shared by both layers) ----
  wt_k<<<512, 256, 0, stream>>>(W1, W2, WT1, WT2);
  hipMemsetAsync(deg, 0, (size_t)NNODES * 4, stream);
  deg_k<<<E8B, 256, 0, stream>>>(dst, deg);
  csr_part_k<<<CSR_NB, 256, 0, stream>>>(deg, bsum);
  csr_mid_k<<<1, 64, 0, stream>>>(bsum, bbase, row_ptr);
  csr_emit_k<<<CSR_NB, 256, 0, stream>>>(deg, bbase, row_ptr, cursor);
  scatter_k<<<E8B, 256, 0, stream>>>(src, dst, cursor, srcoff);

  // ---- layer 1: GEMM(+el/er) -> fused score/softmax/agg (+ELU, fp16) ----
  gemm_k<float><<<MB, 256, 0, stream>>>(feature, WT1, al1, ar1, featH, el, er, NNODES);
  agg_k<1><<<AB, 256, 0, stream>>>(featH, el, er, row_ptr, srcoff, hidH);

  // ---- layer 2: GEMM(+el/er) -> fused agg + head-mean -> d_out ----
  gemm_k<_Float16><<<MB, 256, 0, stream>>>((const _Float16*)hidH, WT2, al2, ar2,
                                           featH, el, er, NNODES);
  agg_k<2><<<AB, 256, 0, stream>>>(featH, el, er, row_ptr, srcoff, out);
}